// Round 1
// baseline (393.275 us; speedup 1.0000x reference)
//
#include <hip/hip_runtime.h>
#include <cstddef>
#include <cstdint>

#define NN 20000
#define NE 640000
#define HD 64

// ---------------- CSR build ----------------
__global__ void hist_kernel(const int* __restrict__ dst, int* __restrict__ cnt) {
    int i = blockIdx.x * blockDim.x + threadIdx.x;
    if (i < NE) atomicAdd(&cnt[dst[i]], 1);
}

__global__ __launch_bounds__(1024) void scan_kernel(const int* __restrict__ cnt,
                                                    int* __restrict__ row_ptr,
                                                    int* __restrict__ cursor) {
    __shared__ int sums[1024];
    int tid = threadIdx.x;
    const int chunk = 20;                 // 1024*20 >= 20000
    int lo = tid * chunk;
    int hi = min(lo + chunk, NN);
    int s = 0;
    for (int i = lo; i < hi; ++i) s += cnt[i];
    sums[tid] = s;
    __syncthreads();
    for (int off = 1; off < 1024; off <<= 1) {
        int v = (tid >= off) ? sums[tid - off] : 0;
        __syncthreads();
        sums[tid] += v;
        __syncthreads();
    }
    int run = sums[tid] - s;              // exclusive prefix of this chunk
    for (int i = lo; i < hi; ++i) {
        row_ptr[i] = run;
        cursor[i] = run;
        run += cnt[i];
    }
    if (tid == 0) row_ptr[NN] = sums[1023];
}

__global__ void place_kernel(const int* __restrict__ src, const int* __restrict__ dst,
                             int* __restrict__ cursor, int* __restrict__ adj_src) {
    int i = blockIdx.x * blockDim.x + threadIdx.x;
    if (i < NE) {
        int d = dst[i];
        int pos = atomicAdd(&cursor[d], 1);
        adj_src[pos] = src[i];
    }
}

// one-time: esum[v] = sum of edge features of incoming edges (round-invariant)
__global__ void esum_kernel(const float* __restrict__ ef, const int* __restrict__ dst,
                            float* __restrict__ esum) {
    int i = blockIdx.x * blockDim.x + threadIdx.x;
    if (i < NE * 16) {
        int e = i >> 4, f = i & 15;
        atomicAdd(&esum[dst[e] * 16 + f], ef[i]);
    }
}

// W_msg [2][144][128] -> WmsgT [2][128][144]  (so GEMM can read B as [N][K])
__global__ void wprep_kernel(const float* __restrict__ W, float* __restrict__ Wt) {
    int i = blockIdx.x * blockDim.x + threadIdx.x;
    if (i < 2 * 144 * 128) {
        int t = i / (144 * 128), rem = i % (144 * 128);
        int k = rem / 128, n = rem % 128;
        Wt[(t * 128 + n) * 144 + k] = W[i];
    }
}

// ---------------- per-round ----------------
// Z[v] = [ deg(v)*hv[v] (64) | S[v]=sum hv[src] (64) | esum[v] (16) ]
__global__ void gather_kernel(const float* __restrict__ hv, const float* __restrict__ esum,
                              const int* __restrict__ row_ptr, const int* __restrict__ adj_src,
                              float* __restrict__ Z, float* __restrict__ degf) {
    int wid = threadIdx.x >> 6;
    int lane = threadIdx.x & 63;
    int v = blockIdx.x * 4 + wid;
    if (v >= NN) return;
    int rp0 = row_ptr[v], rp1 = row_ptr[v + 1];
    float acc = 0.f;
    for (int i = rp0; i < rp1; ++i) {
        int s = adj_src[i];
        acc += hv[s * HD + lane];
    }
    float dg = (float)(rp1 - rp0);
    Z[v * 144 + lane] = dg * hv[v * HD + lane];
    Z[v * 144 + 64 + lane] = acc;
    if (lane < 16) Z[v * 144 + 128 + lane] = esum[v * 16 + lane];
    if (lane == 0) degf[v] = dg;
}

// C[M,N] = A[M,K] @ B[N,K]^T + bias[n] * (bscale ? bscale[m] : 1)
// tile 128x64, BK=32, 256 threads, 8x4 register tile per thread
__global__ __launch_bounds__(256) void gemm_abt(
    const float* __restrict__ A, const float* __restrict__ B,
    const float* __restrict__ bias, const float* __restrict__ bscale,
    float* __restrict__ C, int M, int N, int K) {
    const int BK = 32;
    __shared__ float As[32][132];   // [k][row], +4 pad
    __shared__ float Bs[32][68];    // [k][col], +4 pad
    int tid = threadIdx.x;
    int ty = tid >> 4, tx = tid & 15;     // 16x16 thread grid
    int row0 = blockIdx.x * 128;
    int col0 = blockIdx.y * 64;
    float acc[8][4];
#pragma unroll
    for (int i = 0; i < 8; ++i)
#pragma unroll
        for (int j = 0; j < 4; ++j) acc[i][j] = 0.f;

    int lr = tid >> 3;          // 0..31
    int lk = (tid & 7) << 2;    // 0,4,...,28

    for (int k0 = 0; k0 < K; k0 += BK) {
        // A tile: 128 rows x 32 k (transposed into LDS)
#pragma unroll
        for (int p = 0; p < 4; ++p) {
            int r = lr + p * 32;
            float4 v = make_float4(0.f, 0.f, 0.f, 0.f);
            int gr = row0 + r, gk = k0 + lk;
            if (gr < M && gk < K) v = *(const float4*)(A + (size_t)gr * K + gk);
            As[lk + 0][r] = v.x; As[lk + 1][r] = v.y;
            As[lk + 2][r] = v.z; As[lk + 3][r] = v.w;
        }
        // B tile: 64 cols x 32 k
#pragma unroll
        for (int p = 0; p < 2; ++p) {
            int n = lr + p * 32;
            float4 v = make_float4(0.f, 0.f, 0.f, 0.f);
            int gk = k0 + lk;
            if (gk < K) v = *(const float4*)(B + (size_t)(col0 + n) * K + gk);
            Bs[lk + 0][n] = v.x; Bs[lk + 1][n] = v.y;
            Bs[lk + 2][n] = v.z; Bs[lk + 3][n] = v.w;
        }
        __syncthreads();
#pragma unroll
        for (int kk = 0; kk < BK; ++kk) {
            float4 a0 = *(const float4*)&As[kk][ty * 8];
            float4 a1 = *(const float4*)&As[kk][ty * 8 + 4];
            float4 b0 = *(const float4*)&Bs[kk][tx * 4];
            float av[8] = {a0.x, a0.y, a0.z, a0.w, a1.x, a1.y, a1.z, a1.w};
            float bv[4] = {b0.x, b0.y, b0.z, b0.w};
#pragma unroll
            for (int i = 0; i < 8; ++i)
#pragma unroll
                for (int j = 0; j < 4; ++j)
                    acc[i][j] = fmaf(av[i], bv[j], acc[i][j]);
        }
        __syncthreads();
    }

    int c = col0 + tx * 4;
#pragma unroll
    for (int i = 0; i < 8; ++i) {
        int r = row0 + ty * 8 + i;
        if (r >= M) continue;
        float bs = bscale ? bscale[r] : 1.f;
        float4 o;
        o.x = acc[i][0] + bias[c + 0] * bs;
        o.y = acc[i][1] + bias[c + 1] * bs;
        o.z = acc[i][2] + bias[c + 2] * bs;
        o.w = acc[i][3] + bias[c + 3] * bs;
        *(float4*)(C + (size_t)r * N + c) = o;
    }
}

// GRU gates: out = (1-z)*n + z*h
__global__ void gate_kernel(const float* __restrict__ gi, const float* __restrict__ gh,
                            const float* __restrict__ hv, float* __restrict__ out) {
    int idx = blockIdx.x * blockDim.x + threadIdx.x;
    if (idx >= NN * 64) return;
    int m = idx >> 6, j = idx & 63;
    const float* gim = gi + (size_t)m * 192;
    const float* ghm = gh + (size_t)m * 192;
    float r = 1.f / (1.f + __expf(-(gim[j] + ghm[j])));
    float z = 1.f / (1.f + __expf(-(gim[64 + j] + ghm[64 + j])));
    float hn = ghm[128 + j];
    float n = tanhf(gim[128 + j] + r * hn);
    out[idx] = (1.f - z) * n + z * hv[idx];
}

extern "C" void kernel_launch(void* const* d_in, const int* in_sizes, int n_in,
                              void* d_out, int out_size, void* d_ws, size_t ws_size,
                              hipStream_t stream) {
    const float* hv0   = (const float*)d_in[0];
    const float* ef    = (const float*)d_in[1];
    const int*   src   = (const int*)d_in[2];
    const int*   dst   = (const int*)d_in[3];
    const float* W_msg = (const float*)d_in[4];
    const float* b_msg = (const float*)d_in[5];
    const float* W_ih  = (const float*)d_in[6];
    const float* W_hh  = (const float*)d_in[7];
    const float* b_ih  = (const float*)d_in[8];
    const float* b_hh  = (const float*)d_in[9];
    float* out = (float*)d_out;

    char* ws = (char*)d_ws;
    size_t off = 0;
    auto alloc = [&](size_t bytes) -> char* {
        char* p = ws + off;
        off = (off + bytes + 255) & ~(size_t)255;
        return p;
    };
    int*   cnt     = (int*)alloc(NN * 4);
    int*   row_ptr = (int*)alloc((NN + 1) * 4);
    int*   cursor  = (int*)alloc(NN * 4);
    int*   adj_src = (int*)alloc(NE * 4);
    float* esum    = (float*)alloc(NN * 16 * 4);
    float* degf    = (float*)alloc(NN * 4);
    float* Z       = (float*)alloc((size_t)NN * 144 * 4);
    float* abuf    = (float*)alloc((size_t)NN * 128 * 4);
    float* gi      = (float*)alloc((size_t)NN * 192 * 4);
    float* gh      = (float*)alloc((size_t)NN * 192 * 4);
    float* hv1     = (float*)alloc((size_t)NN * 64 * 4);
    float* WmsgT   = (float*)alloc(2 * 144 * 128 * 4);

    hipMemsetAsync(cnt, 0, NN * 4, stream);
    hipMemsetAsync(esum, 0, NN * 16 * 4, stream);

    hist_kernel<<<(NE + 255) / 256, 256, 0, stream>>>(dst, cnt);
    scan_kernel<<<1, 1024, 0, stream>>>(cnt, row_ptr, cursor);
    place_kernel<<<(NE + 255) / 256, 256, 0, stream>>>(src, dst, cursor, adj_src);
    esum_kernel<<<(NE * 16 + 255) / 256, 256, 0, stream>>>(ef, dst, esum);
    wprep_kernel<<<(2 * 144 * 128 + 255) / 256, 256, 0, stream>>>(W_msg, WmsgT);

    for (int t = 0; t < 2; ++t) {
        const float* hin = (t == 0) ? hv0 : hv1;
        float* hout = (t == 1) ? out : hv1;
        gather_kernel<<<(NN + 3) / 4, 256, 0, stream>>>(hin, esum, row_ptr, adj_src, Z, degf);
        dim3 g1((NN + 127) / 128, 2);
        gemm_abt<<<g1, 256, 0, stream>>>(Z, WmsgT + (size_t)t * 128 * 144,
                                         b_msg + t * 128, degf, abuf, NN, 128, 144);
        dim3 g2((NN + 127) / 128, 3);
        gemm_abt<<<g2, 256, 0, stream>>>(abuf, W_ih + (size_t)t * 192 * 128,
                                         b_ih + t * 192, nullptr, gi, NN, 192, 128);
        gemm_abt<<<g2, 256, 0, stream>>>(hin, W_hh + (size_t)t * 192 * 64,
                                         b_hh + t * 192, nullptr, gh, NN, 192, 64);
        gate_kernel<<<(NN * 64 + 255) / 256, 256, 0, stream>>>(gi, gh, hin, hout);
    }
}

// Round 2
// 310.330 us; speedup vs baseline: 1.2673x; 1.2673x over previous
//
#include <hip/hip_runtime.h>
#include <cstddef>
#include <cstdint>

#define NN 20000
#define NE 640000
#define HD 64

// ---------------- CSR build ----------------
__global__ void hist_kernel(const int* __restrict__ dst, int* __restrict__ cnt) {
    int i = blockIdx.x * blockDim.x + threadIdx.x;
    if (i < NE) atomicAdd(&cnt[dst[i]], 1);
}

__global__ __launch_bounds__(1024) void scan_kernel(const int* __restrict__ cnt,
                                                    int* __restrict__ row_ptr,
                                                    int* __restrict__ cursor) {
    __shared__ int sums[1024];
    int tid = threadIdx.x;
    const int chunk = 20;                 // 1024*20 >= 20000
    int lo = tid * chunk;
    int hi = min(lo + chunk, NN);
    int s = 0;
    for (int i = lo; i < hi; ++i) s += cnt[i];
    sums[tid] = s;
    __syncthreads();
    for (int off = 1; off < 1024; off <<= 1) {
        int v = (tid >= off) ? sums[tid - off] : 0;
        __syncthreads();
        sums[tid] += v;
        __syncthreads();
    }
    int run = sums[tid] - s;              // exclusive prefix of this chunk
    for (int i = lo; i < hi; ++i) {
        row_ptr[i] = run;
        cursor[i] = run;
        run += cnt[i];
    }
    if (tid == 0) row_ptr[NN] = sums[1023];
}

__global__ void place_kernel(const int* __restrict__ src, const int* __restrict__ dst,
                             int* __restrict__ cursor, int* __restrict__ adj_src,
                             int* __restrict__ adj_eid) {
    int i = blockIdx.x * blockDim.x + threadIdx.x;
    if (i < NE) {
        int d = dst[i];
        int pos = atomicAdd(&cursor[d], 1);
        adj_src[pos] = src[i];
        adj_eid[pos] = i;
    }
}

// esum[v] = sum of incoming-edge features (round-invariant), CSR-based, no atomics.
// Also writes degf. One wave per node; quarter-waves stride the edge list.
__global__ __launch_bounds__(256) void esum_csr_kernel(
        const float* __restrict__ ef, const int* __restrict__ row_ptr,
        const int* __restrict__ adj_eid, float* __restrict__ esum,
        float* __restrict__ degf) {
    int wid = threadIdx.x >> 6, lane = threadIdx.x & 63;
    int v = blockIdx.x * 4 + wid;
    if (v >= NN) return;
    int rp0 = row_ptr[v], rp1 = row_ptr[v + 1];
    int q = lane >> 4, f = lane & 15;
    float eacc = 0.f;
    for (int i = rp0 + q; i < rp1; i += 4) {
        int eid = adj_eid[i];
        eacc += ef[(size_t)eid * 16 + f];
    }
    eacc += __shfl_xor(eacc, 16);
    eacc += __shfl_xor(eacc, 32);
    if (lane < 16) esum[(size_t)v * 16 + f] = eacc;
    if (lane == 0) degf[v] = (float)(rp1 - rp0);
}

// Fold: WcT[t][j][k] = sum_m W_msg[t][k][m] * W_ih[t][j][m]   (j<192, k<144)
//       bvec[t][j]   = sum_m b_msg[t][m]    * W_ih[t][j][m]
// grid = 2*9 blocks (t, k-chunk of 16), 192 threads (j).
__global__ __launch_bounds__(192) void fold_kernel(
        const float* __restrict__ W_msg, const float* __restrict__ b_msg,
        const float* __restrict__ W_ih, float* __restrict__ WcT,
        float* __restrict__ bvec) {
    __shared__ float ldsW[64][193];   // [m-sub][j], padded
    int t = blockIdx.x / 9;
    int k0 = (blockIdx.x % 9) * 16;
    int j = threadIdx.x;
    float acc[16];
#pragma unroll
    for (int kk = 0; kk < 16; ++kk) acc[kk] = 0.f;
    float bacc = 0.f;
    for (int mc = 0; mc < 2; ++mc) {
        // stage W_ih[t][:, mc*64 .. +64) transposed
        for (int i = threadIdx.x; i < 192 * 64; i += 192) {
            int jj = i >> 6, mm = i & 63;
            ldsW[mm][jj] = W_ih[((size_t)t * 192 + jj) * 128 + mc * 64 + mm];
        }
        __syncthreads();
        for (int mm = 0; mm < 64; ++mm) {
            float wl = ldsW[mm][j];
            float bm = b_msg[t * 128 + mc * 64 + mm];
            bacc = fmaf(bm, wl, bacc);
#pragma unroll
            for (int kk = 0; kk < 16; ++kk) {
                float wm = W_msg[((size_t)t * 144 + k0 + kk) * 128 + mc * 64 + mm];
                acc[kk] = fmaf(wm, wl, acc[kk]);
            }
        }
        __syncthreads();
    }
#pragma unroll
    for (int kk = 0; kk < 16; ++kk)
        WcT[((size_t)t * 192 + j) * 144 + k0 + kk] = acc[kk];
    if (k0 == 0) bvec[t * 192 + j] = bacc;
}

// ---------------- per-round ----------------
// Z[v] = [ deg(v)*hv[v] (64) | S[v]=sum hv[src] (64) | esum[v] (16) ]
// One wave per node. 16 lanes x float4 per edge; 4 edges in flight per wave,
// unrolled x4 -> 16 outstanding float4 gathers.
__global__ __launch_bounds__(256) void gather_kernel(
        const float* __restrict__ hv, const float* __restrict__ esum,
        const int* __restrict__ row_ptr, const int* __restrict__ adj_src,
        float* __restrict__ Z) {
    int wid = threadIdx.x >> 6, lane = threadIdx.x & 63;
    int v = blockIdx.x * 4 + wid;
    if (v >= NN) return;
    int rp0 = row_ptr[v], rp1 = row_ptr[v + 1];
    int q = lane >> 4;
    int fo = (lane & 15) << 2;
    float4 a0 = make_float4(0.f, 0.f, 0.f, 0.f), a1 = a0, a2 = a0, a3 = a0;
    int i = rp0 + q;
    for (; i + 12 < rp1; i += 16) {
        int s0 = adj_src[i];
        int s1 = adj_src[i + 4];
        int s2 = adj_src[i + 8];
        int s3 = adj_src[i + 12];
        float4 x0 = *(const float4*)(hv + (size_t)s0 * 64 + fo);
        float4 x1 = *(const float4*)(hv + (size_t)s1 * 64 + fo);
        float4 x2 = *(const float4*)(hv + (size_t)s2 * 64 + fo);
        float4 x3 = *(const float4*)(hv + (size_t)s3 * 64 + fo);
        a0.x += x0.x; a0.y += x0.y; a0.z += x0.z; a0.w += x0.w;
        a1.x += x1.x; a1.y += x1.y; a1.z += x1.z; a1.w += x1.w;
        a2.x += x2.x; a2.y += x2.y; a2.z += x2.z; a2.w += x2.w;
        a3.x += x3.x; a3.y += x3.y; a3.z += x3.z; a3.w += x3.w;
    }
    for (; i < rp1; i += 4) {
        int s = adj_src[i];
        float4 x = *(const float4*)(hv + (size_t)s * 64 + fo);
        a0.x += x.x; a0.y += x.y; a0.z += x.z; a0.w += x.w;
    }
    a0.x += a1.x + a2.x + a3.x;
    a0.y += a1.y + a2.y + a3.y;
    a0.z += a1.z + a2.z + a3.z;
    a0.w += a1.w + a2.w + a3.w;
#pragma unroll
    for (int m = 16; m < 64; m <<= 1) {
        a0.x += __shfl_xor(a0.x, m);
        a0.y += __shfl_xor(a0.y, m);
        a0.z += __shfl_xor(a0.z, m);
        a0.w += __shfl_xor(a0.w, m);
    }
    float dg = (float)(rp1 - rp0);
    if (lane < 16) {
        float4 hvv = *(const float4*)(hv + (size_t)v * 64 + fo);
        float4 zh = make_float4(dg * hvv.x, dg * hvv.y, dg * hvv.z, dg * hvv.w);
        *(float4*)(Z + (size_t)v * 144 + fo) = zh;
        *(float4*)(Z + (size_t)v * 144 + 64 + fo) = a0;
    } else if (lane < 20) {
        int f2 = (lane - 16) << 2;
        *(float4*)(Z + (size_t)v * 144 + 128 + f2) =
            *(const float4*)(esum + (size_t)v * 16 + f2);
    }
}

// C[M,N] = A[M,K] @ B[N,K]^T + bias_s[n]*bscale[m] + bias_f[n]
// tile 128x64, BK=32, 256 threads, 8x4 register tile per thread
__global__ __launch_bounds__(256) void gemm_abt(
    const float* __restrict__ A, const float* __restrict__ B,
    const float* __restrict__ bias_s, const float* __restrict__ bscale,
    const float* __restrict__ bias_f,
    float* __restrict__ C, int M, int N, int K) {
    const int BK = 32;
    __shared__ float As[32][132];   // [k][row], +4 pad
    __shared__ float Bs[32][68];    // [k][col], +4 pad
    int tid = threadIdx.x;
    int ty = tid >> 4, tx = tid & 15;     // 16x16 thread grid
    int row0 = blockIdx.x * 128;
    int col0 = blockIdx.y * 64;
    float acc[8][4];
#pragma unroll
    for (int i = 0; i < 8; ++i)
#pragma unroll
        for (int j = 0; j < 4; ++j) acc[i][j] = 0.f;

    int lr = tid >> 3;          // 0..31
    int lk = (tid & 7) << 2;    // 0,4,...,28

    for (int k0 = 0; k0 < K; k0 += BK) {
#pragma unroll
        for (int p = 0; p < 4; ++p) {
            int r = lr + p * 32;
            float4 v = make_float4(0.f, 0.f, 0.f, 0.f);
            int gr = row0 + r, gk = k0 + lk;
            if (gr < M && gk < K) v = *(const float4*)(A + (size_t)gr * K + gk);
            As[lk + 0][r] = v.x; As[lk + 1][r] = v.y;
            As[lk + 2][r] = v.z; As[lk + 3][r] = v.w;
        }
#pragma unroll
        for (int p = 0; p < 2; ++p) {
            int n = lr + p * 32;
            float4 v = make_float4(0.f, 0.f, 0.f, 0.f);
            int gk = k0 + lk;
            if (gk < K) v = *(const float4*)(B + (size_t)(col0 + n) * K + gk);
            Bs[lk + 0][n] = v.x; Bs[lk + 1][n] = v.y;
            Bs[lk + 2][n] = v.z; Bs[lk + 3][n] = v.w;
        }
        __syncthreads();
#pragma unroll
        for (int kk = 0; kk < BK; ++kk) {
            float4 a0 = *(const float4*)&As[kk][ty * 8];
            float4 a1 = *(const float4*)&As[kk][ty * 8 + 4];
            float4 b0 = *(const float4*)&Bs[kk][tx * 4];
            float av[8] = {a0.x, a0.y, a0.z, a0.w, a1.x, a1.y, a1.z, a1.w};
            float bv[4] = {b0.x, b0.y, b0.z, b0.w};
#pragma unroll
            for (int i = 0; i < 8; ++i)
#pragma unroll
                for (int j = 0; j < 4; ++j)
                    acc[i][j] = fmaf(av[i], bv[j], acc[i][j]);
        }
        __syncthreads();
    }

    int c = col0 + tx * 4;
#pragma unroll
    for (int i = 0; i < 8; ++i) {
        int r = row0 + ty * 8 + i;
        if (r >= M) continue;
        float bs = bscale[r];
        float4 o;
        o.x = acc[i][0] + bias_s[c + 0] * bs + bias_f[c + 0];
        o.y = acc[i][1] + bias_s[c + 1] * bs + bias_f[c + 1];
        o.z = acc[i][2] + bias_s[c + 2] * bs + bias_f[c + 2];
        o.w = acc[i][3] + bias_s[c + 3] * bs + bias_f[c + 3];
        *(float4*)(C + (size_t)r * N + c) = o;
    }
}

// Fused gh-GEMM + GRU gates. W_hh [192][64] staged transposed in LDS.
// One wave per row, grid-stride. out = (1-z)*n + z*h
__global__ __launch_bounds__(256) void gru_fused_kernel(
        const float* __restrict__ gi, const float* __restrict__ hin,
        const float* __restrict__ W_hh, const float* __restrict__ b_hh,
        float* __restrict__ out) {
    __shared__ float Wt[64][193];   // [k][j], padded (conflict-free both ways)
    __shared__ float bh[192];
    __shared__ float hrow[4][64];
    for (int i = threadIdx.x; i < 192 * 64; i += 256) {
        int j = i >> 6, k = i & 63;          // coalesced global read
        Wt[k][j] = W_hh[i];
    }
    if (threadIdx.x < 192) bh[threadIdx.x] = b_hh[threadIdx.x];
    __syncthreads();
    int wid = threadIdx.x >> 6, lane = threadIdx.x & 63;
    for (int row = blockIdx.x * 4 + wid; row < NN; row += gridDim.x * 4) {
        float h = hin[(size_t)row * 64 + lane];
        const float* gim = gi + (size_t)row * 192;
        float gr = gim[lane], gz = gim[64 + lane], gn = gim[128 + lane];
        hrow[wid][lane] = h;
        float ar = 0.f, az = 0.f, an = 0.f;
#pragma unroll
        for (int k = 0; k < 64; ++k) {
            float hk = hrow[wid][k];         // broadcast read
            ar = fmaf(hk, Wt[k][lane], ar);
            az = fmaf(hk, Wt[k][64 + lane], az);
            an = fmaf(hk, Wt[k][128 + lane], an);
        }
        float r = 1.f / (1.f + __expf(-(gr + ar + bh[lane])));
        float z = 1.f / (1.f + __expf(-(gz + az + bh[64 + lane])));
        float n = tanhf(gn + r * (an + bh[128 + lane]));
        out[(size_t)row * 64 + lane] = (1.f - z) * n + z * h;
    }
}

extern "C" void kernel_launch(void* const* d_in, const int* in_sizes, int n_in,
                              void* d_out, int out_size, void* d_ws, size_t ws_size,
                              hipStream_t stream) {
    const float* hv0   = (const float*)d_in[0];
    const float* ef    = (const float*)d_in[1];
    const int*   src   = (const int*)d_in[2];
    const int*   dst   = (const int*)d_in[3];
    const float* W_msg = (const float*)d_in[4];
    const float* b_msg = (const float*)d_in[5];
    const float* W_ih  = (const float*)d_in[6];
    const float* W_hh  = (const float*)d_in[7];
    const float* b_ih  = (const float*)d_in[8];
    const float* b_hh  = (const float*)d_in[9];
    float* out = (float*)d_out;

    char* ws = (char*)d_ws;
    size_t off = 0;
    auto alloc = [&](size_t bytes) -> char* {
        char* p = ws + off;
        off = (off + bytes + 255) & ~(size_t)255;
        return p;
    };
    int*   cnt     = (int*)alloc(NN * 4);
    int*   row_ptr = (int*)alloc((NN + 1) * 4);
    int*   cursor  = (int*)alloc(NN * 4);
    int*   adj_src = (int*)alloc(NE * 4);
    int*   adj_eid = (int*)alloc(NE * 4);
    float* esum    = (float*)alloc((size_t)NN * 16 * 4);
    float* degf    = (float*)alloc(NN * 4);
    float* Z       = (float*)alloc((size_t)NN * 144 * 4);
    float* gi      = (float*)alloc((size_t)NN * 192 * 4);
    float* hv1     = (float*)alloc((size_t)NN * 64 * 4);
    float* WcT     = (float*)alloc((size_t)2 * 192 * 144 * 4);
    float* bvec    = (float*)alloc(2 * 192 * 4);

    hipMemsetAsync(cnt, 0, NN * 4, stream);

    hist_kernel<<<(NE + 255) / 256, 256, 0, stream>>>(dst, cnt);
    scan_kernel<<<1, 1024, 0, stream>>>(cnt, row_ptr, cursor);
    place_kernel<<<(NE + 255) / 256, 256, 0, stream>>>(src, dst, cursor, adj_src, adj_eid);
    esum_csr_kernel<<<(NN + 3) / 4, 256, 0, stream>>>(ef, row_ptr, adj_eid, esum, degf);
    fold_kernel<<<18, 192, 0, stream>>>(W_msg, b_msg, W_ih, WcT, bvec);

    for (int t = 0; t < 2; ++t) {
        const float* hin = (t == 0) ? hv0 : hv1;
        float* hout = (t == 1) ? out : hv1;
        gather_kernel<<<(NN + 3) / 4, 256, 0, stream>>>(hin, esum, row_ptr, adj_src, Z);
        dim3 g1((NN + 127) / 128, 3);
        gemm_abt<<<g1, 256, 0, stream>>>(Z, WcT + (size_t)t * 192 * 144,
                                         bvec + t * 192, degf, b_ih + (size_t)t * 192,
                                         gi, NN, 192, 144);
        gru_fused_kernel<<<256, 256, 0, stream>>>(gi, hin, W_hh + (size_t)t * 192 * 64,
                                                  b_hh + t * 192, hout);
    }
}